// Round 4
// baseline (316.954 us; speedup 1.0000x reference)
//
#include <hip/hip_runtime.h>
#include <hip/hip_bf16.h>
#include <stdint.h>

// ---- problem constants ----
#define B64   64
#define DIMS  120
#define NLOC  (DIMS*DIMS)      // 14400 V1 locations
#define V4D   29
#define NLOC4 (V4D*V4D)        // 841 V4 locations

typedef __attribute__((ext_vector_type(8))) short bf16x8;  // 8 bf16 in 4 VGPRs
typedef __attribute__((ext_vector_type(4))) float f32x4;

__device__ __forceinline__ unsigned short f2bf(float f) {
    unsigned u = __float_as_uint(f);
    u += 0x7fffu + ((u >> 16) & 1u);   // round-to-nearest-even
    return (unsigned short)(u >> 16);
}

// ------------------------------------------------------------------
// k0: pack x into two bf16 replica tensors with b innermost for coalesced
// MFMA A-fragment loads (16 lanes x 16B = 256B contiguous per quarter):
//   xrep [r][col][g][b][q]  = x[b][8g+r+q][col]   (rows chunked)
//   xrepT[rc][row][gc][b][q] = x[b][row][8gc+rc+q] (cols chunked)
// ------------------------------------------------------------------
__global__ __launch_bounds__(256) void k0_pack(const float* __restrict__ x,
                                               unsigned short* __restrict__ xrep,
                                               unsigned short* __restrict__ xrepT) {
    __shared__ unsigned short tile[16 * 16 * 64];   // [d1][d2][b]
    int blk = blockIdx.x;
    int isT = (blk >= 128) ? 1 : 0;
    int b2 = blk - 128 * isT;
    int g = b2 >> 3;             // chunk index 0..15
    int fb = (b2 & 7) << 4;      // fixed-dim block base
    int tid = threadIdx.x;
    int bb = tid >> 2, c4 = (tid & 3) << 2;
#pragma unroll 4
    for (int rr = 0; rr < 16; ++rr) {
        int row, col;
        if (!isT) { row = 8 * g + rr; col = fb + c4; }
        else      { row = fb + rr;    col = 8 * g + c4; }
        f32x4 v;
        if (row < 128 && col < 128)
            v = *(const f32x4*)(x + ((size_t)bb * 128 + row) * 128 + col);
        else
            v = (f32x4){0.f, 0.f, 0.f, 0.f};
#pragma unroll
        for (int cc = 0; cc < 4; ++cc) {
            int d1 = isT ? rr : (c4 + cc);
            int d2 = isT ? (c4 + cc) : rr;
            tile[(d1 * 16 + d2) * 64 + bb] = f2bf(v[cc]);
        }
    }
    __syncthreads();
    unsigned short* outp = isT ? xrepT : xrep;
    int b = tid & 63;
#pragma unroll
    for (int it = 0; it < 32; ++it) {
        int u = (it * 256 + tid) >> 6;   // 0..127
        int d1 = u & 15, rq = u >> 4;    // rq = r (or rc), 0..7
        bf16x8 pk;
#pragma unroll
        for (int q = 0; q < 8; ++q)
            pk[q] = (short)tile[(d1 * 16 + rq + q) * 64 + b];
        size_t off = ((((size_t)rq * 128 + (fb + d1)) * 16 + g) * 64 + b) * 8;
        *(bf16x8*)(outp + off) = pk;
    }
}

// ------------------------------------------------------------------
// k0b: permute simple_weight into MFMA-B fragment-major bf16 layout:
//   swp[loc][ch][c][jj], ch = 0..11 (slot = ch*8+jj):
//     e < 72 : slot = kw*8 + kh   (e = kh*9 + kw)
//     e 72-80: slot = e           (ch9: kh=8 row; ch10 jj0: corner)
//     slots 81..95 = 0 (pad)
// One block per location; LDS bounce so global writes are linear b128.
// k1 then loads B-fragments directly from global, coalesced.
// ------------------------------------------------------------------
__global__ __launch_bounds__(256) void k0b_swp(const float* __restrict__ sw,
                                               unsigned short* __restrict__ swp) {
    __shared__ __align__(16) unsigned short stg[32 * 104];   // 6656 B
    int tid = threadIdx.x;
    int loc = blockIdx.x;            // 14400
    // zero pad slots 81..95
    if (tid < 32) {
        unsigned short* rp = stg + tid * 104;
#pragma unroll
        for (int z = 81; z < 96; ++z) rp[z] = 0;
    }
    // elements 0..79 of each c: 640 f32x4 chunks, scatter into stg
#pragma unroll
    for (int it = 0; it < 3; ++it) {
        int idx = it * 256 + tid;
        if (idx < 640) {
            int c = idx / 20, r4 = idx - c * 20;
            f32x4 v = *(const f32x4*)(sw + ((size_t)c * NLOC + loc) * 81 + r4 * 4);
#pragma unroll
            for (int qq = 0; qq < 4; ++qq) {
                int e = r4 * 4 + qq;           // 0..79
                int kh = e / 9, kw = e - 9 * kh;
                int slot = (e < 72) ? (kw * 8 + kh) : e;
                stg[c * 104 + slot] = f2bf(v[qq]);
            }
        }
    }
    // element 80 (corner)
    if (tid < 32)
        stg[tid * 104 + 80] = f2bf(sw[((size_t)tid * NLOC + loc) * 81 + 80]);
    __syncthreads();
    // writeout: 384 b128 chunks, linear in (ch, c) -> fully coalesced
#pragma unroll
    for (int it = 0; it < 2; ++it) {
        int idx = it * 256 + tid;
        if (idx < 384) {
            int ch = idx >> 5, c = idx & 31;
            bf16x8 pk = *(const bf16x8*)(stg + c * 104 + ch * 8);
            *(bf16x8*)(swp + (((size_t)loc * 12 + ch) * 32 + c) * 8) = pk;
        }
    }
}

// ------------------------------------------------------------------
// k1: V1 locally-connected + relu + phase-mean. One wave per location,
// 4 consecutive locations per block. K = 96 (3 MFMA K-steps),
// chunk ch = ks*4 + t:
//   ch 0..8 : patch col kw=ch, rows i..i+7   -> xrep  (kh = jj)
//   ch 9    : row i+8, cols j..j+7           -> xrepT (kw = jj)
//   ch 10   : row i+8, col j+8 (jj==0 only)  -> xrepT at gc+1
//   ch 11   : pad (swp zeros)
// A-frags AND B-frags are single coalesced 16B global loads (swp is
// fragment-major). No weight staging; LDS only for the epilogue pool.
// ------------------------------------------------------------------
__global__ __launch_bounds__(256) void k1_v1(const unsigned short* __restrict__ xrep,
                                             const unsigned short* __restrict__ xrepT,
                                             const unsigned short* __restrict__ swp,
                                             unsigned short* __restrict__ cplx) {
    __shared__ float pool2[4 * 64 * 9];   // 9216 B
    int tid = threadIdx.x;
    int blk = blockIdx.x;
    int blk2 = (blk & 7) * 450 + (blk >> 3);   // XCD band swizzle (3600 = 8*450)
    int loc0 = blk2 * 4;

    int w = tid >> 6, l = tid & 63;
    int loc = loc0 + w;
    int i = loc / DIMS, j = loc - i * DIMS;
    int ln = l & 15, t = l >> 4;
    int r = i & 7, g = i >> 3, rc = j & 7, gc = j >> 3;
    const unsigned short* swl = swp + (size_t)loc * 12 * 32 * 8;

    f32x4 acc[4][2];
#pragma unroll
    for (int mt = 0; mt < 4; ++mt)
#pragma unroll
        for (int nt = 0; nt < 2; ++nt)
            acc[mt][nt] = (f32x4){0.f, 0.f, 0.f, 0.f};

#pragma unroll
    for (int ks = 0; ks < 3; ++ks) {
        int ch = ks * 4 + t;
        // ---- A fragments ----
        const unsigned short* abase;
        if (ks < 2) {
            int col = j + ch;    // ch <= 7 here
            abase = xrep + (((size_t)r * 128 + col) * 16 + g) * 512;
        } else {
            const unsigned short* a0 = xrep + (((size_t)r * 128 + (j + 8)) * 16 + g) * 512;
            int gc2 = gc + ((t >= 2) ? 1 : 0);
            const unsigned short* a1 = xrepT + (((size_t)rc * 128 + (i + 8)) * 16 + gc2) * 512;
            abase = (t == 0) ? a0 : a1;
        }
        bf16x8 a[4];
#pragma unroll
        for (int mt = 0; mt < 4; ++mt)
            a[mt] = *(const bf16x8*)(abase + (size_t)(ln + 16 * mt) * 8);
        // ---- B fragments: one coalesced 16B global load each ----
        bf16x8 bfr[2];
#pragma unroll
        for (int nt = 0; nt < 2; ++nt)
            bfr[nt] = *(const bf16x8*)(swl + ((size_t)ch * 32 + ln + 16 * nt) * 8);
        // ---- MFMAs ----
#pragma unroll
        for (int mt = 0; mt < 4; ++mt)
#pragma unroll
            for (int nt = 0; nt < 2; ++nt)
                acc[mt][nt] = __builtin_amdgcn_mfma_f32_16x16x32_bf16(
                    a[mt], bfr[nt], acc[mt][nt], 0, 0, 0);
    }

    // ---- epilogue: relu, phase-mean via shfl_xor, LDS transpose, store ----
    float* pl = pool2 + w * 64 * 9;
#pragma unroll
    for (int mt = 0; mt < 4; ++mt)
#pragma unroll
        for (int nt = 0; nt < 2; ++nt)
#pragma unroll
            for (int reg = 0; reg < 4; ++reg) {
                float v = fmaxf(acc[mt][nt][reg], 0.0f);
                v += __shfl_xor(v, 1, 64);
                v += __shfl_xor(v, 2, 64);
                if ((ln & 3) == 0) {
                    int b = 16 * mt + 4 * t + reg;
                    int s = 4 * nt + (ln >> 2);
                    pl[b * 9 + s] = v * 0.25f;
                }
            }
    __syncthreads();
    bf16x8 po;
#pragma unroll
    for (int s = 0; s < 8; ++s)
        po[s] = (short)f2bf(pl[l * 9 + s]);
    *(bf16x8*)(cplx + (size_t)loc * 512 + l * 8) = po;
}

// ------------------------------------------------------------------
// k2: V4 pooling. One block per location; vw slice staged bf16 in LDS as
// stg2[pos][o][s] (16 KB) so each B-frag is ONE ds_read_b128.
// 4 waves split K (4 MFMA K-steps each), LDS reduce across waves.
// ------------------------------------------------------------------
__global__ __launch_bounds__(256) void k2_v4(const unsigned short* __restrict__ cplx,
                                             const float* __restrict__ vw,
                                             float* __restrict__ v4s) {
    __shared__ __align__(16) char smraw[16384];
    unsigned short* stg2 = (unsigned short*)smraw;   // [64 pos][16 o][8 s] bf16
    float* pool = (float*)smraw;                     // [4][64][16] fp32 (overlaid)

    int tid = threadIdx.x;
    int blk = blockIdx.x;
    int loc = (blk < 840) ? ((blk & 7) * 105 + (blk >> 3)) : 840;  // XCD band swizzle
    int oi = loc / V4D, oj = loc - oi * V4D;

    // ---- stage vw[.,.,loc,.]: 2048 dwordx4 coalesced, bf16-convert ----
#pragma unroll
    for (int it = 0; it < 8; ++it) {
        int idx = it * 256 + tid;
        int row = idx >> 4, p4 = (idx & 15) * 4;     // row = o*8+s
        f32x4 v = *(const f32x4*)(vw + ((size_t)row * NLOC4 + loc) * 64 + p4);
        int o = row >> 3, s = row & 7;
#pragma unroll
        for (int qq = 0; qq < 4; ++qq)
            stg2[((p4 + qq) * 16 + o) * 8 + s] = f2bf(v[qq]);
    }
    __syncthreads();

    int w = tid >> 6, l = tid & 63;
    int ln = l & 15, t = l >> 4;
    f32x4 acc[4];
#pragma unroll
    for (int mt = 0; mt < 4; ++mt) acc[mt] = (f32x4){0.f, 0.f, 0.f, 0.f};

#pragma unroll
    for (int kk = 0; kk < 4; ++kk) {
        int pos = 4 * (w * 4 + kk) + t;      // 0..63
        int kh = pos >> 3, kw = pos & 7;
        int iloc = (oi * 4 + kh) * DIMS + oj * 4 + kw;
        const unsigned short* ab = cplx + (size_t)iloc * 512 + ln * 8;
        bf16x8 a[4];
#pragma unroll
        for (int mt = 0; mt < 4; ++mt)
            a[mt] = *(const bf16x8*)(ab + mt * 128);
        bf16x8 bb = *(const bf16x8*)(stg2 + (pos * 16 + ln) * 8);
#pragma unroll
        for (int mt = 0; mt < 4; ++mt)
            acc[mt] = __builtin_amdgcn_mfma_f32_16x16x32_bf16(a[mt], bb, acc[mt], 0, 0, 0);
    }
    __syncthreads();                       // stg2 dead; pool overlays
#pragma unroll
    for (int mt = 0; mt < 4; ++mt)
#pragma unroll
        for (int reg = 0; reg < 4; ++reg)
            pool[((w * 64) + 16 * mt + 4 * t + reg) * 16 + ln] = acc[mt][reg];
    __syncthreads();
    int o = tid & 15, brow = tid >> 4;
#pragma unroll
    for (int itb = 0; itb < 4; ++itb) {
        int b = brow + 16 * itb;
        float s = pool[(0 * 64 + b) * 16 + o] + pool[(1 * 64 + b) * 16 + o] +
                  pool[(2 * 64 + b) * 16 + o] + pool[(3 * 64 + b) * 16 + o];
        v4s[(size_t)loc * 1024 + b * 16 + o] = s;
    }
}

// ------------------------------------------------------------------
// k3: decision readout. One block per batch element.
// ------------------------------------------------------------------
__global__ __launch_bounds__(256) void k3_dec(const float* __restrict__ v4s,
                                              const float* __restrict__ dw,
                                              const float* __restrict__ db,
                                              float* __restrict__ out) {
    int b = blockIdx.x, tid = threadIdx.x;
    float a0 = 0.f, a1 = 0.f;
    for (int loc = tid; loc < NLOC4; loc += 256) {
        const float* vp = v4s + (size_t)loc * 1024 + b * 16;
#pragma unroll
        for (int o4 = 0; o4 < 4; ++o4) {
            f32x4 v = *(const f32x4*)(vp + o4 * 4);
#pragma unroll
            for (int q = 0; q < 4; ++q) {
                int o = o4 * 4 + q;
                a0 += v[q] * dw[o * NLOC4 + loc];
                a1 += v[q] * dw[16 * NLOC4 + o * NLOC4 + loc];
            }
        }
    }
    __shared__ float r0[256], r1[256];
    r0[tid] = a0; r1[tid] = a1;
    __syncthreads();
    for (int s = 128; s > 0; s >>= 1) {
        if (tid < s) { r0[tid] += r0[tid + s]; r1[tid] += r1[tid + s]; }
        __syncthreads();
    }
    if (tid == 0) {
        out[2 * b + 0] = r0[0] + db[0];
        out[2 * b + 1] = r1[0] + db[1];
    }
}

// ------------------------------------------------------------------
extern "C" void kernel_launch(void* const* d_in, const int* in_sizes, int n_in,
                              void* d_out, int out_size, void* d_ws, size_t ws_size,
                              hipStream_t stream) {
    const float* x  = (const float*)d_in[0];   // [64][1][128][128]
    const float* sw = (const float*)d_in[1];   // [32][120][120][81]
    const float* vw = (const float*)d_in[2];   // [16][8][29][29][64]
    const float* dw = (const float*)d_in[3];   // [2][13456]
    const float* db = (const float*)d_in[4];   // [2]
    float* out = (float*)d_out;                // [64][2]

    char* ws = (char*)d_ws;
    unsigned short* xrep  = (unsigned short*)ws;                         // 16,777,216 B
    unsigned short* xrepT = (unsigned short*)(ws + 16777216);            // 16,777,216 B
    unsigned short* cplx  = (unsigned short*)(ws + 33554432);            // 14,745,600 B
    float*          v4s   = (float*)(ws + 48300032);                     //  3,444,736 B
    unsigned short* swp   = (unsigned short*)(ws + 51744768);            // 88,473,600 B

    k0_pack<<<256, 256, 0, stream>>>(x, xrep, xrepT);
    k0b_swp<<<NLOC, 256, 0, stream>>>(sw, swp);
    k1_v1<<<NLOC / 4, 256, 0, stream>>>(xrep, xrepT, swp, cplx);
    k2_v4<<<NLOC4, 256, 0, stream>>>(cplx, vw, v4s);
    k3_dec<<<B64, 256, 0, stream>>>(v4s, dw, db, out);
}

// Round 5
// 285.813 us; speedup vs baseline: 1.1090x; 1.1090x over previous
//
#include <hip/hip_runtime.h>
#include <hip/hip_bf16.h>
#include <stdint.h>

// ---- problem constants ----
#define B64   64
#define DIMS  120
#define NLOC  (DIMS*DIMS)      // 14400 V1 locations
#define V4D   29
#define NLOC4 (V4D*V4D)        // 841 V4 locations

typedef __attribute__((ext_vector_type(8))) short bf16x8;  // 8 bf16 in 4 VGPRs
typedef __attribute__((ext_vector_type(4))) float f32x4;

__device__ __forceinline__ unsigned short f2bf(float f) {
    unsigned u = __float_as_uint(f);
    u += 0x7fffu + ((u >> 16) & 1u);   // round-to-nearest-even
    return (unsigned short)(u >> 16);
}

// async global->LDS, 16B per lane (DMA; no VALU, no VGPR round-trip)
__device__ __forceinline__ void gload16(const float* g, float* l) {
    __builtin_amdgcn_global_load_lds(
        (const __attribute__((address_space(1))) unsigned int*)g,
        (__attribute__((address_space(3))) unsigned int*)l, 16, 0, 0);
}

// ------------------------------------------------------------------
// k0: pack x into two bf16 replica tensors with b innermost for coalesced
// MFMA A-fragment loads (16 lanes x 16B = 256B contiguous per quarter):
//   xrep [r][col][g][b][q]  = x[b][8g+r+q][col]   (rows chunked)
//   xrepT[rc][row][gc][b][q] = x[b][row][8gc+rc+q] (cols chunked)
// ------------------------------------------------------------------
__global__ __launch_bounds__(256) void k0_pack(const float* __restrict__ x,
                                               unsigned short* __restrict__ xrep,
                                               unsigned short* __restrict__ xrepT) {
    __shared__ unsigned short tile[16 * 16 * 64];   // [d1][d2][b]
    int blk = blockIdx.x;
    int isT = (blk >= 128) ? 1 : 0;
    int b2 = blk - 128 * isT;
    int g = b2 >> 3;             // chunk index 0..15
    int fb = (b2 & 7) << 4;      // fixed-dim block base
    int tid = threadIdx.x;
    int bb = tid >> 2, c4 = (tid & 3) << 2;
#pragma unroll 4
    for (int rr = 0; rr < 16; ++rr) {
        int row, col;
        if (!isT) { row = 8 * g + rr; col = fb + c4; }
        else      { row = fb + rr;    col = 8 * g + c4; }
        f32x4 v;
        if (row < 128 && col < 128)
            v = *(const f32x4*)(x + ((size_t)bb * 128 + row) * 128 + col);
        else
            v = (f32x4){0.f, 0.f, 0.f, 0.f};
#pragma unroll
        for (int cc = 0; cc < 4; ++cc) {
            int d1 = isT ? rr : (c4 + cc);
            int d2 = isT ? (c4 + cc) : rr;
            tile[(d1 * 16 + d2) * 64 + bb] = f2bf(v[cc]);
        }
    }
    __syncthreads();
    unsigned short* outp = isT ? xrepT : xrep;
    int b = tid & 63;
#pragma unroll
    for (int it = 0; it < 32; ++it) {
        int u = (it * 256 + tid) >> 6;   // 0..127
        int d1 = u & 15, rq = u >> 4;    // rq = r (or rc), 0..7
        bf16x8 pk;
#pragma unroll
        for (int q = 0; q < 8; ++q)
            pk[q] = (short)tile[(d1 * 16 + rq + q) * 64 + b];
        size_t off = ((((size_t)rq * 128 + (fb + d1)) * 16 + g) * 64 + b) * 8;
        *(bf16x8*)(outp + off) = pk;
    }
}

// ------------------------------------------------------------------
// k1: V1 locally-connected + relu + phase-mean. One wave per location,
// 4 consecutive locations per block. K = 96 (3 MFMA K-steps),
// chunk ch = ks*4 + t:
//   ch 0..8 : patch col kw=ch, rows i..i+7   -> xrep  (e = jj*9+ch)
//   ch 9    : row i+8, cols j..j+7           -> xrepT (e = 72+jj)
//   ch 10   : row i+8, col j+8 (jj==0 only)  -> xrepT at gc+1 (e = 80)
//   ch 11   : pad (masked to zero)
// Weights staged RAW fp32 via global_load_lds DMA: stage[c][loc4][81]
// (1296B per c, contiguous & 16B-aligned in sw). Zero staging VALU/LDS-ops.
// B-frags assembled read-side: 8 ds_read_b32 (stride 36B) + f2bf.
// ------------------------------------------------------------------
__global__ __launch_bounds__(256) void k1_v1(const unsigned short* __restrict__ xrep,
                                             const unsigned short* __restrict__ xrepT,
                                             const float* __restrict__ sw,
                                             unsigned short* __restrict__ cplx) {
    __shared__ __align__(16) char smraw[41472];     // 32c * 324 f32
    float* stagef = (float*)smraw;                   // [c][w][81] fp32
    float* pool2 = (float*)smraw;                    // [w][64][9] fp32 (overlay, post-barrier)

    int tid = threadIdx.x;
    int blk = blockIdx.x;
    int blk2 = (blk & 7) * 450 + (blk >> 3);   // XCD band swizzle (3600 = 8*450)
    int loc0 = blk2 * 4;

    int w = tid >> 6, l = tid & 63;

    // ---- stage sw for 4 locations via global->LDS DMA (wave w: c = 8w..8w+7)
#pragma unroll
    for (int cc = 0; cc < 8; ++cc) {
        int c = w * 8 + cc;
        const float* g = sw + ((size_t)c * NLOC + loc0) * 81;   // 1296B, 16B-aligned
        float* lp = stagef + c * 324;
        gload16(g + l * 4, lp + l * 4);                          // bytes 0..1023
        if (l < 17)
            gload16(g + 256 + l * 4, lp + 256 + l * 4);          // bytes 1024..1295
    }

    int loc = loc0 + w;
    int i = loc / DIMS, j = loc - i * DIMS;
    int ln = l & 15, t = l >> 4;
    int r = i & 7, g2 = i >> 3, rc = j & 7, gc = j >> 3;

    // per-lane B read bases (two n-tiles), fp32 rows
    const float* bb0 = stagef + (size_t)ln * 324 + w * 81;
    const float* bb1 = bb0 + 16 * 324;
    // ks=2 per-lane pattern: off/stride in dwords
    int off2 = (t == 0) ? 8 : ((t == 1) ? 72 : 80);
    int strd2 = (t == 0) ? 9 : ((t == 1) ? 1 : 0);
    bool keep0 = (t <= 2);   // jj==0 valid unless t==3
    bool keepR = (t <= 1);   // jj>=1 valid only for t<=1

    f32x4 acc[4][2];
#pragma unroll
    for (int mt = 0; mt < 4; ++mt)
#pragma unroll
        for (int nt = 0; nt < 2; ++nt)
            acc[mt][nt] = (f32x4){0.f, 0.f, 0.f, 0.f};

    __syncthreads();   // drain DMA (compiler emits vmcnt(0) before barrier)

#pragma unroll
    for (int ks = 0; ks < 3; ++ks) {
        int ch = ks * 4 + t;
        // ---- A fragments (coalesced 16B global loads) ----
        const unsigned short* abase;
        if (ks < 2) {
            int col = j + ch;    // ch <= 7 here
            abase = xrep + (((size_t)r * 128 + col) * 16 + g2) * 512;
        } else {
            const unsigned short* a0 = xrep + (((size_t)r * 128 + (j + 8)) * 16 + g2) * 512;
            int gc2 = gc + ((t >= 2) ? 1 : 0);
            const unsigned short* a1 = xrepT + (((size_t)rc * 128 + (i + 8)) * 16 + gc2) * 512;
            abase = (t == 0) ? a0 : a1;
        }
        bf16x8 a[4];
#pragma unroll
        for (int mt = 0; mt < 4; ++mt)
            a[mt] = *(const bf16x8*)(abase + (size_t)(ln + 16 * mt) * 8);
        // ---- B fragments: 8 ds_read_b32 + f2bf each ----
        bf16x8 bfr[2];
        if (ks < 2) {
#pragma unroll
            for (int jj = 0; jj < 8; ++jj) {
                bfr[0][jj] = (short)f2bf(bb0[ch + jj * 9]);
                bfr[1][jj] = (short)f2bf(bb1[ch + jj * 9]);
            }
        } else {
            {
                float v0 = bb0[off2], v1 = bb1[off2];
                bfr[0][0] = (short)f2bf(keep0 ? v0 : 0.0f);
                bfr[1][0] = (short)f2bf(keep0 ? v1 : 0.0f);
            }
            int o = off2;
#pragma unroll
            for (int jj = 1; jj < 8; ++jj) {
                o += strd2;
                float v0 = bb0[o], v1 = bb1[o];
                bfr[0][jj] = (short)f2bf(keepR ? v0 : 0.0f);
                bfr[1][jj] = (short)f2bf(keepR ? v1 : 0.0f);
            }
        }
        // ---- MFMAs ----
#pragma unroll
        for (int mt = 0; mt < 4; ++mt)
#pragma unroll
            for (int nt = 0; nt < 2; ++nt)
                acc[mt][nt] = __builtin_amdgcn_mfma_f32_16x16x32_bf16(
                    a[mt], bfr[nt], acc[mt][nt], 0, 0, 0);
    }

    // ---- epilogue: relu, phase-mean via shfl_xor, LDS transpose, store ----
    __syncthreads();                     // stage dead only after ALL waves done
    float* pl = pool2 + w * 64 * 9;
#pragma unroll
    for (int mt = 0; mt < 4; ++mt)
#pragma unroll
        for (int nt = 0; nt < 2; ++nt)
#pragma unroll
            for (int reg = 0; reg < 4; ++reg) {
                float v = fmaxf(acc[mt][nt][reg], 0.0f);
                v += __shfl_xor(v, 1, 64);
                v += __shfl_xor(v, 2, 64);
                if ((ln & 3) == 0) {
                    int b = 16 * mt + 4 * t + reg;
                    int s = 4 * nt + (ln >> 2);
                    pl[b * 9 + s] = v * 0.25f;
                }
            }
    __syncthreads();
    bf16x8 po;
#pragma unroll
    for (int s = 0; s < 8; ++s)
        po[s] = (short)f2bf(pl[l * 9 + s]);
    *(bf16x8*)(cplx + (size_t)loc * 512 + l * 8) = po;
}

// ------------------------------------------------------------------
// k2: V4 pooling. One block per location; vw slice staged RAW fp32 via
// global_load_lds DMA: row ro=o*8+s (256B, 256B-aligned) -> LDS base
// (s*16+o)*68 dwords (272B stride: 16B-aligned bases, 2-way banks).
// B-frag read-side: 8 ds_read_b32 (imm offset s*4352B) + f2bf.
// 4 waves split K, LDS reduce across waves.
// ------------------------------------------------------------------
__global__ __launch_bounds__(256) void k2_v4(const unsigned short* __restrict__ cplx,
                                             const float* __restrict__ vw,
                                             float* __restrict__ v4s) {
    __shared__ __align__(16) char smraw[128 * 68 * 4];   // 34816 B
    float* stg = (float*)smraw;                          // [s*16+o][68] fp32
    float* pool = (float*)smraw;                         // [4][64][16] fp32 (overlay)

    int tid = threadIdx.x;
    int blk = blockIdx.x;
    int loc = (blk < 840) ? ((blk & 7) * 105 + (blk >> 3)) : 840;  // XCD band swizzle
    int oi = loc / V4D, oj = loc - oi * V4D;

    int w = tid >> 6, l = tid & 63;

    // ---- stage vw[.,.,loc,.] via DMA: wave w rows ro = 32w..32w+31 ----
    if (l < 16) {
#pragma unroll
        for (int m = 0; m < 32; ++m) {
            int ro = w * 32 + m;
            int o = ro >> 3, s = ro & 7;
            const float* g = vw + ((size_t)ro * NLOC4 + loc) * 64;   // 256B aligned
            float* lp = stg + (s * 16 + o) * 68;
            gload16(g + l * 4, lp + l * 4);
        }
    }

    int ln = l & 15, t = l >> 4;
    f32x4 acc[4];
#pragma unroll
    for (int mt = 0; mt < 4; ++mt) acc[mt] = (f32x4){0.f, 0.f, 0.f, 0.f};

    __syncthreads();   // drain DMA

    const float* brow = stg + ln * 68;
#pragma unroll
    for (int kk = 0; kk < 4; ++kk) {
        int pos = 4 * (w * 4 + kk) + t;      // 0..63
        int kh = pos >> 3, kw = pos & 7;
        int iloc = (oi * 4 + kh) * DIMS + oj * 4 + kw;
        const unsigned short* ab = cplx + (size_t)iloc * 512 + ln * 8;
        bf16x8 a[4];
#pragma unroll
        for (int mt = 0; mt < 4; ++mt)
            a[mt] = *(const bf16x8*)(ab + mt * 128);
        bf16x8 bb;
#pragma unroll
        for (int s = 0; s < 8; ++s)
            bb[s] = (short)f2bf(brow[s * 16 * 68 + pos]);
#pragma unroll
        for (int mt = 0; mt < 4; ++mt)
            acc[mt] = __builtin_amdgcn_mfma_f32_16x16x32_bf16(a[mt], bb, acc[mt], 0, 0, 0);
    }
    __syncthreads();                       // stg dead; pool overlays
#pragma unroll
    for (int mt = 0; mt < 4; ++mt)
#pragma unroll
        for (int reg = 0; reg < 4; ++reg)
            pool[((w * 64) + 16 * mt + 4 * t + reg) * 16 + ln] = acc[mt][reg];
    __syncthreads();
    int o = tid & 15, brw = tid >> 4;
#pragma unroll
    for (int itb = 0; itb < 4; ++itb) {
        int b = brw + 16 * itb;
        float s = pool[(0 * 64 + b) * 16 + o] + pool[(1 * 64 + b) * 16 + o] +
                  pool[(2 * 64 + b) * 16 + o] + pool[(3 * 64 + b) * 16 + o];
        v4s[(size_t)loc * 1024 + b * 16 + o] = s;
    }
}

// ------------------------------------------------------------------
// k3: decision readout. One block per batch element.
// ------------------------------------------------------------------
__global__ __launch_bounds__(256) void k3_dec(const float* __restrict__ v4s,
                                              const float* __restrict__ dw,
                                              const float* __restrict__ db,
                                              float* __restrict__ out) {
    int b = blockIdx.x, tid = threadIdx.x;
    float a0 = 0.f, a1 = 0.f;
    for (int loc = tid; loc < NLOC4; loc += 256) {
        const float* vp = v4s + (size_t)loc * 1024 + b * 16;
#pragma unroll
        for (int o4 = 0; o4 < 4; ++o4) {
            f32x4 v = *(const f32x4*)(vp + o4 * 4);
#pragma unroll
            for (int q = 0; q < 4; ++q) {
                int o = o4 * 4 + q;
                a0 += v[q] * dw[o * NLOC4 + loc];
                a1 += v[q] * dw[16 * NLOC4 + o * NLOC4 + loc];
            }
        }
    }
    __shared__ float r0[256], r1[256];
    r0[tid] = a0; r1[tid] = a1;
    __syncthreads();
    for (int s = 128; s > 0; s >>= 1) {
        if (tid < s) { r0[tid] += r0[tid + s]; r1[tid] += r1[tid + s]; }
        __syncthreads();
    }
    if (tid == 0) {
        out[2 * b + 0] = r0[0] + db[0];
        out[2 * b + 1] = r1[0] + db[1];
    }
}

// ------------------------------------------------------------------
extern "C" void kernel_launch(void* const* d_in, const int* in_sizes, int n_in,
                              void* d_out, int out_size, void* d_ws, size_t ws_size,
                              hipStream_t stream) {
    const float* x  = (const float*)d_in[0];   // [64][1][128][128]
    const float* sw = (const float*)d_in[1];   // [32][120][120][81]
    const float* vw = (const float*)d_in[2];   // [16][8][29][29][64]
    const float* dw = (const float*)d_in[3];   // [2][13456]
    const float* db = (const float*)d_in[4];   // [2]
    float* out = (float*)d_out;                // [64][2]

    char* ws = (char*)d_ws;
    unsigned short* xrep  = (unsigned short*)ws;                         // 16,777,216 B
    unsigned short* xrepT = (unsigned short*)(ws + 16777216);            // 16,777,216 B
    unsigned short* cplx  = (unsigned short*)(ws + 33554432);            // 14,745,600 B
    float*          v4s   = (float*)(ws + 48300032);                     //  3,444,736 B

    k0_pack<<<256, 256, 0, stream>>>(x, xrep, xrepT);
    k1_v1<<<NLOC / 4, 256, 0, stream>>>(xrep, xrepT, sw, cplx);
    k2_v4<<<NLOC4, 256, 0, stream>>>(cplx, vw, v4s);
    k3_dec<<<B64, 256, 0, stream>>>(v4s, dw, db, out);
}